// Round 11
// baseline (59.424 us; speedup 1.0000x reference)
//
#include <hip/hip_runtime.h>

#define HW 128
#define PLANE (HW * HW)              // 16384
#define SCALE 0.17677669529663687f   // 32^-0.5
#define FENCE() asm volatile("" ::: "memory")

typedef float vfloat4 __attribute__((ext_vector_type(4)));  // native vector for nontemporal builtin

// R9 QK pipeline + fused single store phase + single-generation grid.
// One thread = 4-pixel x-strip x 16 channels; lane = (strip<<1)|h2; wave =
// one image row; block = 2 waves = 2 rows. Channels per thread: g*8 + h2*4 +
// {0..3}, g=0..3. PV accumulates all 16 channels into acc[4][16]; all 16
// float4 stores issue back-to-back at kernel end (pair lanes + sequential
// quads fill 64B sectors -> kills the 1.4x write amplification), nontemporal
// (output never re-read; avoid evicting L3-resident inputs).
// Grid = 4b*4h*64ytiles = 1024 blocks x 2 waves = 2048 waves = 4 blocks/CU
// exactly -> one co-resident generation, no ragged second wave of blocks.
__global__ __launch_bounds__(128, 2) void natt3x3_kernel(
    const float* __restrict__ q,
    const float* __restrict__ k,
    const float* __restrict__ v,
    float* __restrict__ out) {
  const int tid  = threadIdx.x;
  const int lane = tid & 63;
  const int w    = tid >> 6;            // wave index in block = row in tile
  const int h2   = lane & 1;            // channel sub-quad selector
  const int s    = lane >> 1;           // strip 0..31
  const int x0   = s << 2;              // first pixel x of strip
  const int bid  = blockIdx.x;          // ((b*4+head)*64 + ytile)
  const int ytile = bid & 63;
  const int head  = (bid >> 6) & 3;
  const int b     = bid >> 8;
  const int y     = (ytile << 1) | w;

  const size_t cbase = (size_t)(b * 128 + head * 32 + h2 * 4) * PLANE;
  const int yx = y * HW + x0;

  int yrow[3];
#pragma unroll
  for (int dy = 0; dy < 3; ++dy) {
    int yy = y + dy - 1; yy = yy < 0 ? 0 : (yy > HW - 1 ? HW - 1 : yy);
    yrow[dy] = yy * HW;
  }

  float l[4][9];
#pragma unroll
  for (int i = 0; i < 4; ++i)
#pragma unroll
    for (int j = 0; j < 9; ++j) l[i][j] = 0.f;

  float acc[4][16];     // all 16 channels per pixel, stored once at the end
#pragma unroll
  for (int i = 0; i < 4; ++i)
#pragma unroll
    for (int c = 0; c < 16; ++c) acc[i][c] = 0.f;

  float4 qv4[3][4];      // q quads per buffer
  float4 rv[3][3][4];    // k/v rows [buf][dy][c]

#define LQK(B, G) do {                                                       \
    const size_t cb = cbase + (size_t)((G) * 8) * PLANE;                     \
    const float* qg = q + cb + yx;                                           \
    const float* kg = k + cb;                                                \
    _Pragma("unroll")                                                        \
    for (int c = 0; c < 4; ++c)                                              \
      qv4[B][c] = *reinterpret_cast<const float4*>(qg + (size_t)c * PLANE);  \
    _Pragma("unroll")                                                        \
    for (int c = 0; c < 4; ++c)                                              \
      _Pragma("unroll")                                                      \
      for (int dy = 0; dy < 3; ++dy)                                         \
        rv[B][dy][c] = *reinterpret_cast<const float4*>(                     \
            kg + (size_t)c * PLANE + yrow[dy] + x0);                         \
  } while (0)

#define LPV(B, G) do {                                                       \
    const float* vg = v + cbase + (size_t)((G) * 8) * PLANE;                 \
    _Pragma("unroll")                                                        \
    for (int c = 0; c < 4; ++c)                                              \
      _Pragma("unroll")                                                      \
      for (int dy = 0; dy < 3; ++dy)                                         \
        rv[B][dy][c] = *reinterpret_cast<const float4*>(                     \
            vg + (size_t)c * PLANE + yrow[dy] + x0);                         \
  } while (0)

#define CQK(B) do {                                                          \
    _Pragma("unroll")                                                        \
    for (int c = 0; c < 4; ++c) {                                            \
      const float qa[4] = {qv4[B][c].x * SCALE, qv4[B][c].y * SCALE,         \
                           qv4[B][c].z * SCALE, qv4[B][c].w * SCALE};        \
      _Pragma("unroll")                                                      \
      for (int dy = 0; dy < 3; ++dy) {                                       \
        float4 kq = rv[B][dy][c];                                            \
        float n0 = __shfl_up(kq.w, 2);                                       \
        float n5 = __shfl_down(kq.x, 2);                                     \
        const float n[6] = {n0, kq.x, kq.y, kq.z, kq.w, n5};                 \
        _Pragma("unroll")                                                    \
        for (int i = 0; i < 4; ++i)                                          \
          _Pragma("unroll")                                                  \
          for (int j = 0; j < 3; ++j)                                        \
            l[i][dy * 3 + j] += qa[i] * n[i + j];                            \
      }                                                                      \
    }                                                                        \
  } while (0)

#define CPV(B, G) do {                                                       \
    _Pragma("unroll")                                                        \
    for (int c = 0; c < 4; ++c)                                              \
      _Pragma("unroll")                                                      \
      for (int dy = 0; dy < 3; ++dy) {                                       \
        float4 vq = rv[B][dy][c];                                            \
        float n0 = __shfl_up(vq.w, 2);                                       \
        float n5 = __shfl_down(vq.x, 2);                                     \
        const float n[6] = {n0, vq.x, vq.y, vq.z, vq.w, n5};                 \
        _Pragma("unroll")                                                    \
        for (int i = 0; i < 4; ++i)                                          \
          _Pragma("unroll")                                                  \
          for (int j = 0; j < 3; ++j)                                        \
            acc[i][(G) * 4 + c] += l[i][dy * 3 + j] * n[i + j];              \
      }                                                                      \
  } while (0)

  // ---- QK: fence-pinned schedule, 2-3 load-groups in flight ----
  LQK(0, 0); FENCE();
  LQK(1, 1); FENCE();
  LQK(2, 2); FENCE();
  CQK(0);    FENCE();
  LQK(0, 3); FENCE();
  CQK(1);    FENCE();
  LPV(1, 0); FENCE();
  CQK(2);    FENCE();
  LPV(2, 1); FENCE();
  CQK(0);    FENCE();   // group 3
  LPV(0, 2); FENCE();

  // ---- lane-pair reduce: my 16 channels + partner's 16 = full 32 ----
#pragma unroll
  for (int i = 0; i < 4; ++i)
#pragma unroll
    for (int j = 0; j < 9; ++j) l[i][j] += __shfl_xor(l[i][j], 1);

  // ---- mask + softmax per pixel (3 PV load-groups in flight under this) ----
#pragma unroll
  for (int i = 0; i < 4; ++i) {
    const int xp = x0 + i;
    float mk[9];
#pragma unroll
    for (int dy = 0; dy < 3; ++dy)
#pragma unroll
      for (int dx = 0; dx < 3; ++dx) {
        bool ok = ((unsigned)(y + dy - 1) < (unsigned)HW) &&
                  ((unsigned)(xp + dx - 1) < (unsigned)HW);
        mk[dy * 3 + dx] = ok ? 1.f : 0.f;
      }
    float m = -1e30f;
#pragma unroll
    for (int j = 0; j < 9; ++j) {
      float t = l[i][j] * mk[j];
      l[i][j] = t;
      m = fmaxf(m, t);
    }
    float sum = 0.f;
#pragma unroll
    for (int j = 0; j < 9; ++j) {
      float e = __expf(l[i][j] - m);
      l[i][j] = e;
      sum += e;
    }
    float inv = 1.f / sum;
#pragma unroll
    for (int j = 0; j < 9; ++j) l[i][j] *= inv * mk[j];
  }
  FENCE();

  // ---- PV: accumulate only (no stores yet) ----
  CPV(1, 0); FENCE();
  LPV(1, 3); FENCE();
  CPV(2, 1); FENCE();
  CPV(0, 2); FENCE();
  CPV(1, 3);

  // ---- single store phase: 16 nontemporal float4, back-to-back ----
  // pair lanes (h2 0/1) + sequential g cover whole 64B sectors per pixel.
  const size_t obase = ((size_t)(b * PLANE + y * HW)) * 128 + head * 32 + h2 * 4;
#pragma unroll
  for (int i = 0; i < 4; ++i) {
    float* op = out + obase + (size_t)(x0 + i) * 128;
#pragma unroll
    for (int g = 0; g < 4; ++g) {
      vfloat4 o;
      o.x = fmaxf(acc[i][g * 4 + 0], 0.f);
      o.y = fmaxf(acc[i][g * 4 + 1], 0.f);
      o.z = fmaxf(acc[i][g * 4 + 2], 0.f);
      o.w = fmaxf(acc[i][g * 4 + 3], 0.f);
      __builtin_nontemporal_store(o, reinterpret_cast<vfloat4*>(op + g * 8));
    }
  }

#undef LQK
#undef LPV
#undef CQK
#undef CPV
}

extern "C" void kernel_launch(void* const* d_in, const int* in_sizes, int n_in,
                              void* d_out, int out_size, void* d_ws, size_t ws_size,
                              hipStream_t stream) {
  const float* q = (const float*)d_in[0];
  const float* k = (const float*)d_in[1];
  const float* v = (const float*)d_in[2];
  float* out = (float*)d_out;
  // grid: B(4) * heads(4) * ytiles(64) = 1024 blocks, 128 threads (2 waves)
  natt3x3_kernel<<<1024, 128, 0, stream>>>(q, k, v, out);
}

// Round 12
// 29.458 us; speedup vs baseline: 2.0173x; 2.0173x over previous
//
#include <hip/hip_runtime.h>

#define HW 128
#define PLANE (HW * HW)              // 16384
#define SCALE 0.17677669529663687f   // 32^-0.5
#define FENCE() asm volatile("" ::: "memory")

// R9 structure with 8-row tiles (halo 1.25x vs 1.5x) + fused NORMAL store
// phase (R11's nontemporal stores bypassed L2 merge -> reverted).
// One thread = 4-pixel x-strip x 16 channels; lane = (strip<<1)|h2; wave =
// one image row; block = 8 waves = 8 rows. Channels per thread: g*8 + h2*4 +
// {0..3}, g=0..3 (pair-contiguous 32B stores, quads sequential -> 64B
// sectors merge in L2). PV accumulates all 16 ch in acc[4][16]; 16 float4
// stores issue back-to-back at the end. Fence-pinned 3-buffer pipeline keeps
// 2-3 load-groups in flight. Grid = 4b*4h*16ytiles = 256 blocks = 1/CU.
__global__ __launch_bounds__(512, 2) void natt3x3_kernel(
    const float* __restrict__ q,
    const float* __restrict__ k,
    const float* __restrict__ v,
    float* __restrict__ out) {
  const int tid  = threadIdx.x;
  const int lane = tid & 63;
  const int w    = tid >> 6;            // wave index in block = row in tile (0..7)
  const int h2   = lane & 1;            // channel sub-quad selector
  const int s    = lane >> 1;           // strip 0..31
  const int x0   = s << 2;              // first pixel x of strip
  const int bid  = blockIdx.x;          // ((b*4+head)*16 + ytile)
  const int ytile = bid & 15;
  const int head  = (bid >> 4) & 3;
  const int b     = bid >> 6;
  const int y     = (ytile << 3) | w;

  const size_t cbase = (size_t)(b * 128 + head * 32 + h2 * 4) * PLANE;
  const int yx = y * HW + x0;

  int yrow[3];
#pragma unroll
  for (int dy = 0; dy < 3; ++dy) {
    int yy = y + dy - 1; yy = yy < 0 ? 0 : (yy > HW - 1 ? HW - 1 : yy);
    yrow[dy] = yy * HW;
  }

  float l[4][9];
#pragma unroll
  for (int i = 0; i < 4; ++i)
#pragma unroll
    for (int j = 0; j < 9; ++j) l[i][j] = 0.f;

  float acc[4][16];     // all 16 channels per pixel, stored once at the end
#pragma unroll
  for (int i = 0; i < 4; ++i)
#pragma unroll
    for (int c = 0; c < 16; ++c) acc[i][c] = 0.f;

  float4 qv4[3][4];      // q quads per buffer
  float4 rv[3][3][4];    // k/v rows [buf][dy][c]

#define LQK(B, G) do {                                                       \
    const size_t cb = cbase + (size_t)((G) * 8) * PLANE;                     \
    const float* qg = q + cb + yx;                                           \
    const float* kg = k + cb;                                                \
    _Pragma("unroll")                                                        \
    for (int c = 0; c < 4; ++c)                                              \
      qv4[B][c] = *reinterpret_cast<const float4*>(qg + (size_t)c * PLANE);  \
    _Pragma("unroll")                                                        \
    for (int c = 0; c < 4; ++c)                                              \
      _Pragma("unroll")                                                      \
      for (int dy = 0; dy < 3; ++dy)                                         \
        rv[B][dy][c] = *reinterpret_cast<const float4*>(                     \
            kg + (size_t)c * PLANE + yrow[dy] + x0);                         \
  } while (0)

#define LPV(B, G) do {                                                       \
    const float* vg = v + cbase + (size_t)((G) * 8) * PLANE;                 \
    _Pragma("unroll")                                                        \
    for (int c = 0; c < 4; ++c)                                              \
      _Pragma("unroll")                                                      \
      for (int dy = 0; dy < 3; ++dy)                                         \
        rv[B][dy][c] = *reinterpret_cast<const float4*>(                     \
            vg + (size_t)c * PLANE + yrow[dy] + x0);                         \
  } while (0)

#define CQK(B) do {                                                          \
    _Pragma("unroll")                                                        \
    for (int c = 0; c < 4; ++c) {                                            \
      const float qa[4] = {qv4[B][c].x * SCALE, qv4[B][c].y * SCALE,         \
                           qv4[B][c].z * SCALE, qv4[B][c].w * SCALE};        \
      _Pragma("unroll")                                                      \
      for (int dy = 0; dy < 3; ++dy) {                                       \
        float4 kq = rv[B][dy][c];                                            \
        float n0 = __shfl_up(kq.w, 2);                                       \
        float n5 = __shfl_down(kq.x, 2);                                     \
        const float n[6] = {n0, kq.x, kq.y, kq.z, kq.w, n5};                 \
        _Pragma("unroll")                                                    \
        for (int i = 0; i < 4; ++i)                                          \
          _Pragma("unroll")                                                  \
          for (int j = 0; j < 3; ++j)                                        \
            l[i][dy * 3 + j] += qa[i] * n[i + j];                            \
      }                                                                      \
    }                                                                        \
  } while (0)

#define CPV(B, G) do {                                                       \
    _Pragma("unroll")                                                        \
    for (int c = 0; c < 4; ++c)                                              \
      _Pragma("unroll")                                                      \
      for (int dy = 0; dy < 3; ++dy) {                                       \
        float4 vq = rv[B][dy][c];                                            \
        float n0 = __shfl_up(vq.w, 2);                                       \
        float n5 = __shfl_down(vq.x, 2);                                     \
        const float n[6] = {n0, vq.x, vq.y, vq.z, vq.w, n5};                 \
        _Pragma("unroll")                                                    \
        for (int i = 0; i < 4; ++i)                                          \
          _Pragma("unroll")                                                  \
          for (int j = 0; j < 3; ++j)                                        \
            acc[i][(G) * 4 + c] += l[i][dy * 3 + j] * n[i + j];              \
      }                                                                      \
  } while (0)

  // ---- QK: fence-pinned schedule, 2-3 load-groups in flight ----
  LQK(0, 0); FENCE();
  LQK(1, 1); FENCE();
  LQK(2, 2); FENCE();
  CQK(0);    FENCE();
  LQK(0, 3); FENCE();
  CQK(1);    FENCE();
  LPV(1, 0); FENCE();
  CQK(2);    FENCE();
  LPV(2, 1); FENCE();
  CQK(0);    FENCE();   // group 3
  LPV(0, 2); FENCE();

  // ---- lane-pair reduce: my 16 channels + partner's 16 = full 32 ----
#pragma unroll
  for (int i = 0; i < 4; ++i)
#pragma unroll
    for (int j = 0; j < 9; ++j) l[i][j] += __shfl_xor(l[i][j], 1);

  // ---- mask + softmax per pixel (3 PV load-groups in flight under this) ----
#pragma unroll
  for (int i = 0; i < 4; ++i) {
    const int xp = x0 + i;
    float mk[9];
#pragma unroll
    for (int dy = 0; dy < 3; ++dy)
#pragma unroll
      for (int dx = 0; dx < 3; ++dx) {
        bool ok = ((unsigned)(y + dy - 1) < (unsigned)HW) &&
                  ((unsigned)(xp + dx - 1) < (unsigned)HW);
        mk[dy * 3 + dx] = ok ? 1.f : 0.f;
      }
    float m = -1e30f;
#pragma unroll
    for (int j = 0; j < 9; ++j) {
      float t = l[i][j] * mk[j];
      l[i][j] = t;
      m = fmaxf(m, t);
    }
    float sum = 0.f;
#pragma unroll
    for (int j = 0; j < 9; ++j) {
      float e = __expf(l[i][j] - m);
      l[i][j] = e;
      sum += e;
    }
    float inv = 1.f / sum;
#pragma unroll
    for (int j = 0; j < 9; ++j) l[i][j] *= inv * mk[j];
  }
  FENCE();

  // ---- PV: accumulate only (no stores yet) ----
  CPV(1, 0); FENCE();
  LPV(1, 3); FENCE();
  CPV(2, 1); FENCE();
  CPV(0, 2); FENCE();
  CPV(1, 3);

  // ---- single store phase: 16 normal float4, back-to-back ----
  // pair lanes (h2 0/1) + sequential g cover whole 64B sectors -> L2 merges.
  const size_t obase = ((size_t)(b * PLANE + y * HW)) * 128 + head * 32 + h2 * 4;
#pragma unroll
  for (int i = 0; i < 4; ++i) {
    float* op = out + obase + (size_t)(x0 + i) * 128;
#pragma unroll
    for (int g = 0; g < 4; ++g) {
      float4 o;
      o.x = fmaxf(acc[i][g * 4 + 0], 0.f);
      o.y = fmaxf(acc[i][g * 4 + 1], 0.f);
      o.z = fmaxf(acc[i][g * 4 + 2], 0.f);
      o.w = fmaxf(acc[i][g * 4 + 3], 0.f);
      *reinterpret_cast<float4*>(op + g * 8) = o;
    }
  }

#undef LQK
#undef LPV
#undef CQK
#undef CPV
}

extern "C" void kernel_launch(void* const* d_in, const int* in_sizes, int n_in,
                              void* d_out, int out_size, void* d_ws, size_t ws_size,
                              hipStream_t stream) {
  const float* q = (const float*)d_in[0];
  const float* k = (const float*)d_in[1];
  const float* v = (const float*)d_in[2];
  float* out = (float*)d_out;
  // grid: B(4) * heads(4) * ytiles(16) = 256 blocks, 512 threads (8 waves)
  natt3x3_kernel<<<256, 512, 0, stream>>>(q, k, v, out);
}